// Round 3
// baseline (643.412 us; speedup 1.0000x reference)
//
#include <hip/hip_runtime.h>
#include <hip/hip_bf16.h>
#include <stdint.h>

typedef short bf16x8 __attribute__((ext_vector_type(8)));
typedef float f32x4 __attribute__((ext_vector_type(4)));
typedef unsigned short u16x8 __attribute__((ext_vector_type(8)));

#define GLB(p)  ((__attribute__((address_space(1))) void*)(uintptr_t)(p))
#define LDSP(p) ((__attribute__((address_space(3))) void*)(p))

#define BM 128
#define BN 128
#define BK 32

// Split fp32 into bf16 hi + bf16 lo (both RNE). x ≈ hi + lo with ~2^-18 rel residual.
__device__ __forceinline__ void bf16_split(float x, unsigned short& h, unsigned short& l) {
  unsigned u = __float_as_uint(x);
  unsigned hb = (u + 0x7FFFu + ((u >> 16) & 1u)) >> 16;
  h = (unsigned short)hb;
  float d = x - __uint_as_float(hb << 16);
  unsigned u2 = __float_as_uint(d);
  l = (unsigned short)((u2 + 0x7FFFu + ((u2 >> 16) & 1u)) >> 16);
}

// Prepass 1: elementwise split of x -> A_hi, A_lo ([M][K] bf16, k-contiguous)
__global__ void convert_split_k(const float* __restrict__ in,
                                unsigned short* __restrict__ hi,
                                unsigned short* __restrict__ lo, long n) {
  long i = ((long)blockIdx.x * blockDim.x + threadIdx.x) * 8;
  if (i + 8 > n) return;
  float v[8];
  *(float4*)(&v[0]) = *(const float4*)(in + i);
  *(float4*)(&v[4]) = *(const float4*)(in + i + 4);
  u16x8 vh, vl;
#pragma unroll
  for (int e = 0; e < 8; ++e) {
    unsigned short h, l;
    bf16_split(v[e], h, l);
    vh[e] = h; vl[e] = l;
  }
  *(u16x8*)(hi + i) = vh;
  *(u16x8*)(lo + i) = vl;
}

// Prepass 2: W[Dk][U] fp32 -> Bt_hi, Bt_lo [U][Dk] bf16 (k-contiguous rows).
// Reads coalesced along U (256 lanes x 4B per d); writes 64B contiguous per lane.
__global__ void transpose_split_k(const float* __restrict__ in,
                                  unsigned short* __restrict__ hiT,
                                  unsigned short* __restrict__ loT,
                                  int Dk, int U) {
  const int ublocks = U >> 8;
  const int ub = blockIdx.x % ublocks;
  const int db = blockIdx.x / ublocks;
  const int u  = (ub << 8) + threadIdx.x;
  const int d0 = db * 32;
  unsigned short h[32], l[32];
#pragma unroll
  for (int i = 0; i < 32; ++i) {
    float x = in[(long)(d0 + i) * U + u];
    bf16_split(x, h[i], l[i]);
  }
  u16x8* ph = (u16x8*)(hiT + (long)u * Dk + d0);
  u16x8* pl = (u16x8*)(loT + (long)u * Dk + d0);
#pragma unroll
  for (int q = 0; q < 4; ++q) {
    u16x8 vh, vl;
#pragma unroll
    for (int e = 0; e < 8; ++e) { vh[e] = h[q * 8 + e]; vl[e] = l[q * 8 + e]; }
    ph[q] = vh;
    pl[q] = vl;
  }
}

// Main GEMM: C = hi·hi + hi·lo + lo·hi (bf16x3 fp32-emulation), fused noise epilogue.
// 128x128 tile, BK=32, 4 waves x (64x64), 16x16x32 bf16 MFMA (m97 structure).
// LDS staged via global_load_lds(16B) with pre-swizzled global source so the
// read-side XOR swizzle slot^=(row>>1)&3 is ~2-way (free) on ds_read_b128.
__global__ __launch_bounds__(256) void gemm_bf16x3(
    const unsigned short* __restrict__ Ahi, const unsigned short* __restrict__ Alo,
    const unsigned short* __restrict__ Bhi, const unsigned short* __restrict__ Blo,
    const float* __restrict__ nmean, const float* __restrict__ nstd,
    const float* __restrict__ eps, float* __restrict__ out,
    int M, int N, int K)
{
  __shared__ unsigned short sAhi[BM * BK], sAlo[BM * BK];
  __shared__ unsigned short sBhi[BN * BK], sBlo[BN * BK];

  const int tid  = threadIdx.x;
  const int wid  = tid >> 6;
  const int lane = tid & 63;
  const int l15  = lane & 15;
  const int kg   = lane >> 4;   // k-group for fragments, row-group for C/D

  const int nbm = M / BM, nbn = N / BN, nwg = nbm * nbn;
  const int bid = blockIdx.x;
  const int swz = ((nwg & 7) == 0) ? ((bid & 7) * (nwg >> 3) + (bid >> 3)) : bid;
  const int bm = swz % nbm, bn = swz / nbm;

  const int wm = wid >> 1, wn = wid & 1;
  const int rowA0 = bm * BM;
  const int rowB0 = bn * BN;

  f32x4 acc[4][4];
#pragma unroll
  for (int i = 0; i < 4; ++i)
#pragma unroll
    for (int j = 0; j < 4; ++j) acc[i][j] = (f32x4)0.0f;

  for (int kt = 0; kt < K; kt += BK) {
    // ---- stage 4 tiles (8KB each): wave wid does chunks {2w, 2w+1} of 1KB ----
#pragma unroll
    for (int j = 0; j < 2; ++j) {
      const int c = wid * 2 + j;          // chunk 0..7 (16 rows each)
      const int m = c * 16 + (lane >> 2); // tile row this lane feeds
      const int s = lane & 3;             // 16B slot within the 64B row
      const int g = s ^ ((m >> 1) & 3);   // pre-swizzled source k-group
      const long koff = (long)kt + g * 8;
      const int lofs = c * 512;           // elements (1KB per chunk)
      __builtin_amdgcn_global_load_lds(GLB(Ahi + (long)(rowA0 + m) * K + koff), LDSP(&sAhi[lofs]), 16, 0, 0);
      __builtin_amdgcn_global_load_lds(GLB(Alo + (long)(rowA0 + m) * K + koff), LDSP(&sAlo[lofs]), 16, 0, 0);
      __builtin_amdgcn_global_load_lds(GLB(Bhi + (long)(rowB0 + m) * K + koff), LDSP(&sBhi[lofs]), 16, 0, 0);
      __builtin_amdgcn_global_load_lds(GLB(Blo + (long)(rowB0 + m) * K + koff), LDSP(&sBlo[lofs]), 16, 0, 0);
    }
    __syncthreads();

    // ---- fragment loads (swizzled ds_read_b128) ----
    bf16x8 ah[4], al[4], bh[4], bl[4];
#pragma unroll
    for (int f = 0; f < 4; ++f) {
      const int ma = wm * 64 + f * 16 + l15;
      const int oa = ma * BK + ((kg ^ ((ma >> 1) & 3)) * 8);
      ah[f] = *(const bf16x8*)&sAhi[oa];
      al[f] = *(const bf16x8*)&sAlo[oa];
      const int mb = wn * 64 + f * 16 + l15;
      const int ob = mb * BK + ((kg ^ ((mb >> 1) & 3)) * 8);
      bh[f] = *(const bf16x8*)&sBhi[ob];
      bl[f] = *(const bf16x8*)&sBlo[ob];
    }

    // ---- 48 MFMAs, term-major so same-acc reuses are 16 MFMAs apart ----
#pragma unroll
    for (int i = 0; i < 4; ++i)
#pragma unroll
      for (int j = 0; j < 4; ++j)
        acc[i][j] = __builtin_amdgcn_mfma_f32_16x16x32_bf16(ah[i], bh[j], acc[i][j], 0, 0, 0);
#pragma unroll
    for (int i = 0; i < 4; ++i)
#pragma unroll
      for (int j = 0; j < 4; ++j)
        acc[i][j] = __builtin_amdgcn_mfma_f32_16x16x32_bf16(ah[i], bl[j], acc[i][j], 0, 0, 0);
#pragma unroll
    for (int i = 0; i < 4; ++i)
#pragma unroll
      for (int j = 0; j < 4; ++j)
        acc[i][j] = __builtin_amdgcn_mfma_f32_16x16x32_bf16(al[i], bh[j], acc[i][j], 0, 0, 0);
    __syncthreads();
  }

  // ---- epilogue: C/D layout col=lane&15, row=4*(lane>>4)+r; fuse noise ----
  const float NS = 2.44140625e-4f; // 1/4096 = 2^-12
  const int r0 = rowA0 + wm * 64;
  const int c0 = rowB0 + wn * 64;
#pragma unroll
  for (int i = 0; i < 4; ++i)
#pragma unroll
    for (int j = 0; j < 4; ++j) {
      const int col = c0 + j * 16 + l15;
      const float mn = nmean[col];
      const float sd = nstd[col];
#pragma unroll
      for (int r = 0; r < 4; ++r) {
        const int row = r0 + i * 16 + kg * 4 + r;
        const long o = (long)row * N + col;
        out[o] = acc[i][j][r] + (mn + sd * eps[o]) * NS;
      }
    }
}

// Insurance: plain fp32 LDS-tiled GEMM (used only if ws_size < 134MB or odd shapes).
__global__ __launch_bounds__(1024) void fb_gemm(
    const float* __restrict__ A, const float* __restrict__ B,
    const float* __restrict__ nmean, const float* __restrict__ nstd,
    const float* __restrict__ eps, float* __restrict__ out,
    int M, int N, int K) {
  __shared__ float sA[32][33];
  __shared__ float sB[32][33];
  const int tx = threadIdx.x & 31, ty = threadIdx.x >> 5;
  const int row = blockIdx.y * 32 + ty;
  const int col = blockIdx.x * 32 + tx;
  float acc = 0.f;
  for (int kt = 0; kt < K; kt += 32) {
    sA[ty][tx] = A[(long)row * K + kt + tx];
    sB[ty][tx] = B[(long)(kt + ty) * N + col];
    __syncthreads();
#pragma unroll
    for (int k = 0; k < 32; ++k) acc += sA[ty][k] * sB[k][tx];
    __syncthreads();
  }
  const long o = (long)row * N + col;
  out[o] = acc + (nmean[col] + nstd[col] * eps[o]) * 2.44140625e-4f;
}

extern "C" void kernel_launch(void* const* d_in, const int* in_sizes, int n_in,
                              void* d_out, int out_size, void* d_ws, size_t ws_size,
                              hipStream_t stream) {
  (void)n_in; (void)out_size;
  const float* x     = (const float*)d_in[0];
  const float* w     = (const float*)d_in[1];
  const float* nmean = (const float*)d_in[2];
  const float* nstd  = (const float*)d_in[3];
  const float* eps   = (const float*)d_in[4];
  float* out = (float*)d_out;

  const int U  = in_sizes[2];
  const int Dk = in_sizes[1] / U;
  const int Bm = in_sizes[0] / Dk;

  const size_t elemsA = (size_t)Bm * Dk;
  const size_t elemsB = (size_t)Dk * U;
  const size_t need = 2 * (elemsA + elemsB) * sizeof(unsigned short);

  const bool ok = (ws_size >= need) &&
                  (Bm % BM == 0) && (U % BN == 0) && (Dk % BK == 0) &&
                  (U % 256 == 0) && (Dk % 32 == 0) && ((elemsA % 8) == 0);

  if (ok) {
    unsigned short* Ahi  = (unsigned short*)d_ws;
    unsigned short* Alo  = Ahi + elemsA;
    unsigned short* BhiT = Alo + elemsA;
    unsigned short* BloT = BhiT + elemsB;
    const long nA = (long)elemsA;
    const int gridA = (int)((nA / 8 + 255) / 256);
    convert_split_k<<<gridA, 256, 0, stream>>>(x, Ahi, Alo, nA);
    transpose_split_k<<<(U >> 8) * (Dk / 32), 256, 0, stream>>>(w, BhiT, BloT, Dk, U);
    gemm_bf16x3<<<(Bm / BM) * (U / BN), 256, 0, stream>>>(Ahi, Alo, BhiT, BloT,
                                                          nmean, nstd, eps, out, Bm, U, Dk);
  } else {
    dim3 g(U / 32, Bm / 32);
    fb_gemm<<<g, 1024, 0, stream>>>(x, w, nmean, nstd, eps, out, Bm, U, Dk);
  }
}

// Round 5
// 568.915 us; speedup vs baseline: 1.1309x; 1.1309x over previous
//
#include <hip/hip_runtime.h>
#include <hip/hip_bf16.h>
#include <stdint.h>

typedef short bf16x8 __attribute__((ext_vector_type(8)));
typedef float f32x4 __attribute__((ext_vector_type(4)));
typedef unsigned short u16x8 __attribute__((ext_vector_type(8)));

#define GLB(p)  ((__attribute__((address_space(1))) void*)(uintptr_t)(p))
#define LDSP(p) ((__attribute__((address_space(3))) void*)(p))

// Split fp32 into bf16 hi + bf16 lo (both RNE). x ≈ hi + lo with ~2^-17 rel residual.
__device__ __forceinline__ void bf16_split(float x, unsigned short& h, unsigned short& l) {
  unsigned u = __float_as_uint(x);
  unsigned hb = (u + 0x7FFFu + ((u >> 16) & 1u)) >> 16;
  h = (unsigned short)hb;
  float d = x - __uint_as_float(hb << 16);
  unsigned u2 = __float_as_uint(d);
  l = (unsigned short)((u2 + 0x7FFFu + ((u2 >> 16) & 1u)) >> 16);
}

// Prepass 1: elementwise split of x -> A_hi, A_lo ([M][K] bf16, k-contiguous)
__global__ void convert_split_k(const float* __restrict__ in,
                                unsigned short* __restrict__ hi,
                                unsigned short* __restrict__ lo, long n) {
  long i = ((long)blockIdx.x * blockDim.x + threadIdx.x) * 8;
  if (i + 8 > n) return;
  float v[8];
  *(float4*)(&v[0]) = *(const float4*)(in + i);
  *(float4*)(&v[4]) = *(const float4*)(in + i + 4);
  u16x8 vh, vl;
#pragma unroll
  for (int e = 0; e < 8; ++e) {
    unsigned short h, l;
    bf16_split(v[e], h, l);
    vh[e] = h; vl[e] = l;
  }
  *(u16x8*)(hi + i) = vh;
  *(u16x8*)(lo + i) = vl;
}

// Prepass 2: W[Dk][U] fp32 -> Bt_hi, Bt_lo [U][Dk] bf16 (k-contiguous rows).
__global__ void transpose_split_k(const float* __restrict__ in,
                                  unsigned short* __restrict__ hiT,
                                  unsigned short* __restrict__ loT,
                                  int Dk, int U) {
  const int ublocks = U >> 8;
  const int ub = blockIdx.x % ublocks;
  const int db = blockIdx.x / ublocks;
  const int u  = (ub << 8) + threadIdx.x;
  const int d0 = db * 32;
  unsigned short h[32], l[32];
#pragma unroll
  for (int i = 0; i < 32; ++i) {
    float x = in[(long)(d0 + i) * U + u];
    bf16_split(x, h[i], l[i]);
  }
  u16x8* ph = (u16x8*)(hiT + (long)u * Dk + d0);
  u16x8* pl = (u16x8*)(loT + (long)u * Dk + d0);
#pragma unroll
  for (int q = 0; q < 4; ++q) {
    u16x8 vh, vl;
#pragma unroll
    for (int e = 0; e < 8; ++e) { vh[e] = h[q * 8 + e]; vl[e] = l[q * 8 + e]; }
    ph[q] = vh;
    pl[q] = vl;
  }
}

// ---------------------------------------------------------------------------
// 256x256-tile 6-phase bf16x3 GEMM (T1+T2+T3+T4+T5 stack, m201-style).
// 8 waves (2M x 4N), each owns 128x64 output = 8x4 16x16 fragments.
// BK=32. LDS: 2 buf x {Ahi,Alo,Bhi,Blo} x 16KB = 128KB, double-buffered.
// Phases per K-tile: (hh,h0)(hh,h1)(hl,h0)(hl,h1)(lh,h0)(lh,h1), each
// {ds_read frags | 2x global_load_lds -> barrier -> lgkmcnt(0) -> setprio(1)
//  -> 16 MFMA -> setprio(0) -> barrier}; ONE vmcnt(0) per tile at P6 end
// (T4-ish: staging loads issued P1-P4 stay in flight under ~5 phases of MFMA).
// WAR audit: stage writes buf c^1; buf c^1 reads finished in tile t-1 before
// its P6 vmcnt+barrier, so no hazard. Reads of newly staged buf happen only
// after that same vmcnt(0)+barrier (per-wave vmcnt + barrier = all visible).
// Swizzle (rule #21 involution): store slot s holds kgroup g = s^((row>>1)&3);
// read slot for kg = kg^((row>>1)&3); rows at read are base+l15, base%16==0,
// so masks match the write side exactly -> 2-way conflict (free, m136).
// ---------------------------------------------------------------------------
#define BARRIER0 __builtin_amdgcn_s_barrier()
#define WAIT_LGKM0 do { asm volatile("s_waitcnt lgkmcnt(0)" ::: "memory"); \
                        __builtin_amdgcn_sched_barrier(0); } while (0)
#define WAIT_VM0 asm volatile("s_waitcnt vmcnt(0)" ::: "memory")

#define MFMA_BLOCK(IB) do { \
  __builtin_amdgcn_s_setprio(1); \
  _Pragma("unroll") for (int i_ = 0; i_ < 4; ++i_) \
  _Pragma("unroll") for (int j_ = 0; j_ < 4; ++j_) \
    acc[(IB) + i_][j_] = __builtin_amdgcn_mfma_f32_16x16x32_bf16(aF[i_], bF[j_], acc[(IB) + i_][j_], 0, 0, 0); \
  __builtin_amdgcn_s_setprio(0); } while (0)

#define RD_A(HL, HALF) do { \
  _Pragma("unroll") for (int f_ = 0; f_ < 4; ++f_) \
    aF[f_] = *(const bf16x8*)&sA[c][HL][wm * 4096 + (HALF) * 2048 + f_ * 512 + foff]; } while (0)

#define RD_B(HL) do { \
  _Pragma("unroll") for (int f_ = 0; f_ < 4; ++f_) \
    bF[f_] = *(const bf16x8*)&sB[c][HL][wn * 2048 + f_ * 512 + foff]; } while (0)

#define STAGE2(GSRC, LBASE, KOFF) do { \
  __builtin_amdgcn_global_load_lds(GLB((GSRC) + so0 + (KOFF)), LDSP((LBASE) + (wid << 9)), 16, 0, 0); \
  __builtin_amdgcn_global_load_lds(GLB((GSRC) + so1 + (KOFF)), LDSP((LBASE) + 4096 + (wid << 9)), 16, 0, 0); } while (0)

__global__ __launch_bounds__(512, 2) void gemm_bf16x3_8p(
    const unsigned short* __restrict__ Ahi, const unsigned short* __restrict__ Alo,
    const unsigned short* __restrict__ Bhi, const unsigned short* __restrict__ Blo,
    const float* __restrict__ nmean, const float* __restrict__ nstd,
    const float* __restrict__ eps, float* __restrict__ out,
    int M, int N, int K)
{
  __shared__ __align__(16) unsigned short sA[2][2][256 * 32];
  __shared__ __align__(16) unsigned short sB[2][2][256 * 32];

  const int tid  = threadIdx.x;
  const int wid  = tid >> 6;
  const int lane = tid & 63;
  const int l15  = lane & 15;
  const int kg   = lane >> 4;
  const int wm   = wid >> 2;   // 0..1
  const int wn   = wid & 3;    // 0..3

  const int nbm = M >> 8, nbn = N >> 8, nwg = nbm * nbn;
  const int bid = blockIdx.x;
  const int swz = ((nwg & 7) == 0) ? ((bid & 7) * (nwg >> 3) + (bid >> 3)) : bid;
  const int bm = swz % nbm, bn = swz / nbm;
  const long rowA0 = (long)bm << 8;
  const long rowB0 = (long)bn << 8;

  const unsigned short* gAh = Ahi + rowA0 * K;
  const unsigned short* gAl = Alo + rowA0 * K;
  const unsigned short* gBh = Bhi + rowB0 * K;
  const unsigned short* gBl = Blo + rowB0 * K;

  // staging: thread t feeds 16B chunks e0=tid and e1=tid+512 of each 16KB array
  const int e0 = tid, e1 = tid + 512;
  const int r0 = e0 >> 2, r1 = e1 >> 2;
  const long so0 = (long)r0 * K + (long)(((e0 & 3) ^ ((r0 >> 1) & 3)) << 3);
  const long so1 = (long)r1 * K + (long)(((e1 & 3) ^ ((r1 >> 1) & 3)) << 3);

  // per-lane fragment read offset (elements)
  const int foff = l15 * 32 + ((kg ^ ((l15 >> 1) & 3)) << 3);

  f32x4 acc[8][4];
#pragma unroll
  for (int i = 0; i < 8; ++i)
#pragma unroll
    for (int j = 0; j < 4; ++j) acc[i][j] = (f32x4)0.0f;

  const int nt = K >> 5;

  // prologue: stage tile 0 into buffer 0
  STAGE2(gAh, &sA[0][0][0], 0);
  STAGE2(gAl, &sA[0][1][0], 0);
  STAGE2(gBh, &sB[0][0][0], 0);
  STAGE2(gBl, &sB[0][1][0], 0);
  WAIT_VM0;
  BARRIER0;

  for (int t = 0; t < nt; ++t) {
    const int c = t & 1;
    const long KOFF = (long)(t + 1) << 5;
    const bool pf = (t + 1 < nt);
    unsigned short* nAh = &sA[c ^ 1][0][0];
    unsigned short* nAl = &sA[c ^ 1][1][0];
    unsigned short* nBh = &sB[c ^ 1][0][0];
    unsigned short* nBl = &sB[c ^ 1][1][0];
    bf16x8 aF[4], bF[4];

    // P1: hi*hi, m-half 0
    RD_A(0, 0); RD_B(0);
    if (pf) STAGE2(gAh, nAh, KOFF);
    BARRIER0; WAIT_LGKM0; MFMA_BLOCK(0); BARRIER0;

    // P2: hi*hi, m-half 1 (bF kept in registers)
    RD_A(0, 1);
    if (pf) STAGE2(gAl, nAl, KOFF);
    BARRIER0; WAIT_LGKM0; MFMA_BLOCK(4); BARRIER0;

    // P3: hi*lo, m-half 0
    RD_A(0, 0); RD_B(1);
    if (pf) STAGE2(gBh, nBh, KOFF);
    BARRIER0; WAIT_LGKM0; MFMA_BLOCK(0); BARRIER0;

    // P4: hi*lo, m-half 1
    RD_A(0, 1);
    if (pf) STAGE2(gBl, nBl, KOFF);
    BARRIER0; WAIT_LGKM0; MFMA_BLOCK(4); BARRIER0;

    // P5: lo*hi, m-half 0
    RD_A(1, 0); RD_B(0);
    BARRIER0; WAIT_LGKM0; MFMA_BLOCK(0); BARRIER0;

    // P6: lo*hi, m-half 1; tile-end: drain staging, then barrier
    RD_A(1, 1);
    BARRIER0; WAIT_LGKM0; MFMA_BLOCK(4);
    WAIT_VM0;
    BARRIER0;
  }

  // epilogue: C/D layout col=lane&15, row=4*(lane>>4)+r; fused noise
  const float NS = 2.44140625e-4f; // 2^-12
  const long r0o = rowA0 + wm * 128;
  const long c0o = rowB0 + wn * 64;
#pragma unroll
  for (int i = 0; i < 8; ++i)
#pragma unroll
    for (int j = 0; j < 4; ++j) {
      const long col = c0o + j * 16 + l15;
      const float mn = nmean[col];
      const float sd = nstd[col];
#pragma unroll
      for (int r = 0; r < 4; ++r) {
        const long row = r0o + i * 16 + kg * 4 + r;
        const long o = row * N + col;
        out[o] = acc[i][j][r] + (mn + sd * eps[o]) * NS;
      }
    }
}

// Insurance: plain fp32 LDS-tiled GEMM (only for odd shapes / tiny workspace).
__global__ __launch_bounds__(1024) void fb_gemm(
    const float* __restrict__ A, const float* __restrict__ B,
    const float* __restrict__ nmean, const float* __restrict__ nstd,
    const float* __restrict__ eps, float* __restrict__ out,
    int M, int N, int K) {
  __shared__ float sA[32][33];
  __shared__ float sB[32][33];
  const int tx = threadIdx.x & 31, ty = threadIdx.x >> 5;
  const int row = blockIdx.y * 32 + ty;
  const int col = blockIdx.x * 32 + tx;
  float acc = 0.f;
  for (int kt = 0; kt < K; kt += 32) {
    sA[ty][tx] = A[(long)row * K + kt + tx];
    sB[ty][tx] = B[(long)(kt + ty) * N + col];
    __syncthreads();
#pragma unroll
    for (int k = 0; k < 32; ++k) acc += sA[ty][k] * sB[k][tx];
    __syncthreads();
  }
  const long o = (long)row * N + col;
  out[o] = acc + (nmean[col] + nstd[col] * eps[o]) * 2.44140625e-4f;
}

extern "C" void kernel_launch(void* const* d_in, const int* in_sizes, int n_in,
                              void* d_out, int out_size, void* d_ws, size_t ws_size,
                              hipStream_t stream) {
  (void)n_in; (void)out_size;
  const float* x     = (const float*)d_in[0];
  const float* w     = (const float*)d_in[1];
  const float* nmean = (const float*)d_in[2];
  const float* nstd  = (const float*)d_in[3];
  const float* eps   = (const float*)d_in[4];
  float* out = (float*)d_out;

  const int U  = in_sizes[2];
  const int Dk = in_sizes[1] / U;
  const int Bm = in_sizes[0] / Dk;

  const size_t elemsA = (size_t)Bm * Dk;
  const size_t elemsB = (size_t)Dk * U;
  const size_t need = 2 * (elemsA + elemsB) * sizeof(unsigned short);

  const bool ok = (ws_size >= need) &&
                  (Bm % 256 == 0) && (U % 256 == 0) && (Dk % 32 == 0) &&
                  ((elemsA % 8) == 0);

  if (ok) {
    unsigned short* Ahi  = (unsigned short*)d_ws;
    unsigned short* Alo  = Ahi + elemsA;
    unsigned short* BhiT = Alo + elemsA;
    unsigned short* BloT = BhiT + elemsB;
    const long nA = (long)elemsA;
    const int gridA = (int)((nA / 8 + 255) / 256);
    convert_split_k<<<gridA, 256, 0, stream>>>(x, Ahi, Alo, nA);
    transpose_split_k<<<(U >> 8) * (Dk / 32), 256, 0, stream>>>(w, BhiT, BloT, Dk, U);
    const int nwg = (Bm >> 8) * (U >> 8);
    gemm_bf16x3_8p<<<nwg, 512, 0, stream>>>(Ahi, Alo, BhiT, BloT,
                                            nmean, nstd, eps, out, Bm, U, Dk);
  } else {
    dim3 g(U / 32, Bm / 32);
    fb_gemm<<<g, 1024, 0, stream>>>(x, w, nmean, nstd, eps, out, Bm, U, Dk);
  }
}

// Round 7
// 538.671 us; speedup vs baseline: 1.1944x; 1.0561x over previous
//
#include <hip/hip_runtime.h>
#include <hip/hip_bf16.h>
#include <stdint.h>

typedef short bf16x8 __attribute__((ext_vector_type(8)));
typedef float f32x4 __attribute__((ext_vector_type(4)));
typedef unsigned short u16x8 __attribute__((ext_vector_type(8)));

#define GLB(p)  ((__attribute__((address_space(1))) void*)(uintptr_t)(p))
#define LDSP(p) ((__attribute__((address_space(3))) void*)(p))

// Split fp32 into bf16 hi + bf16 lo (both RNE). x ≈ hi + lo with ~2^-17 rel residual.
__device__ __forceinline__ void bf16_split(float x, unsigned short& h, unsigned short& l) {
  unsigned u = __float_as_uint(x);
  unsigned hb = (u + 0x7FFFu + ((u >> 16) & 1u)) >> 16;
  h = (unsigned short)hb;
  float d = x - __uint_as_float(hb << 16);
  unsigned u2 = __float_as_uint(d);
  l = (unsigned short)((u2 + 0x7FFFu + ((u2 >> 16) & 1u)) >> 16);
}

// Prepass 1: elementwise split of x -> A_hi, A_lo ([M][K] bf16, k-contiguous)
__global__ void convert_split_k(const float* __restrict__ in,
                                unsigned short* __restrict__ hi,
                                unsigned short* __restrict__ lo, long n) {
  long i = ((long)blockIdx.x * blockDim.x + threadIdx.x) * 8;
  if (i + 8 > n) return;
  float v[8];
  *(float4*)(&v[0]) = *(const float4*)(in + i);
  *(float4*)(&v[4]) = *(const float4*)(in + i + 4);
  u16x8 vh, vl;
#pragma unroll
  for (int e = 0; e < 8; ++e) {
    unsigned short h, l;
    bf16_split(v[e], h, l);
    vh[e] = h; vl[e] = l;
  }
  *(u16x8*)(hi + i) = vh;
  *(u16x8*)(lo + i) = vl;
}

// Prepass 2 (LDS-tiled): W[Dk][U] fp32 -> Bt_hi, Bt_lo [U][Dk] bf16.
// Tile = 16 u x 256 d. Reads: lanes cover u (64B aligned runs). Writes: lanes
// 0-31 cover 512B contiguous per output row -> fully coalesced (fixes the
// round-5 ~100+ us prepass gap from 16B-scattered writes).
__global__ __launch_bounds__(256) void transpose_split_k(
    const float* __restrict__ in, unsigned short* __restrict__ hiT,
    unsigned short* __restrict__ loT, int Dk, int U) {
  __shared__ unsigned short lh[16][264];
  __shared__ unsigned short ll[16][264];
  const int t = threadIdx.x;
  const int ublocks = U >> 4;
  const int u0 = (blockIdx.x % ublocks) << 4;
  const int d0 = (blockIdx.x / ublocks) << 8;
  const int ul = t & 15, dl0 = t >> 4;
#pragma unroll
  for (int p = 0; p < 16; ++p) {
    const int d = dl0 + p * 16;
    float x = in[(long)(d0 + d) * U + (u0 + ul)];
    unsigned short h, l;
    bf16_split(x, h, l);
    lh[ul][d] = h;
    ll[ul][d] = l;
  }
  __syncthreads();
  const int ur = t >> 5, ck = t & 31;
#pragma unroll
  for (int p = 0; p < 2; ++p) {
    const int u = ur + p * 8;
    u16x8 vh = *(const u16x8*)&lh[u][ck * 8];
    u16x8 vl = *(const u16x8*)&ll[u][ck * 8];
    *(u16x8*)(hiT + (long)(u0 + u) * Dk + d0 + ck * 8) = vh;
    *(u16x8*)(loT + (long)(u0 + u) * Dk + d0 + ck * 8) = vl;
  }
}

// ---------------------------------------------------------------------------
// 256x256-tile 2-phase bf16x3 GEMM. 8 waves (2M x 4N), each 128x64 output.
// BK=32. LDS: 2 buf x {Ahi,Alo,Bhi,Blo} x 16KB = 128KB double-buffered.
// Per K-tile: P1 {read 8 B-frags (hi+lo, tile-resident) + 8 A-frags (m-half 0)
// | issue all 8 stage loads -> barrier -> lgkm0 -> 48 MFMA}, P2 {8 A-frags
// (m-half 1) -> barrier -> lgkm0 -> 48 MFMA -> vmcnt(0) -> barrier}.
// Round-5 post-mortem: 6 phases gave 16 MFMA (~154 cyc/SIMD) per ~150 cyc of
// barrier overhead -> 47% MfmaUtil. 2 phases give 48 MFMA per phase.
// WAR/RAW invariants: reads from buf c, stages to buf c^1; tile-end
// vmcnt(0)+barrier publishes staged data; buf c^1 reads finished at previous
// tile's lgkm0 before any new stage issue crosses a barrier.
// Swizzle (rule #21 involution, verified r3): store slot s of row r holds
// kgroup s^((r>>1)&3); read slot kg^((l15>>1)&3) -> 2-way LDS (free, m136).
// ---------------------------------------------------------------------------
#define BARRIER0 __builtin_amdgcn_s_barrier()
#define WAIT_LGKM0 do { asm volatile("s_waitcnt lgkmcnt(0)" ::: "memory"); \
                        __builtin_amdgcn_sched_barrier(0); } while (0)
#define WAIT_VM0 asm volatile("s_waitcnt vmcnt(0)" ::: "memory")

#define MFMA_BLOCK3(IB) do { \
  __builtin_amdgcn_s_setprio(1); \
  _Pragma("unroll") for (int i_ = 0; i_ < 4; ++i_) \
  _Pragma("unroll") for (int j_ = 0; j_ < 4; ++j_) \
    acc[(IB)+i_][j_] = __builtin_amdgcn_mfma_f32_16x16x32_bf16(aFh[i_], bFh[j_], acc[(IB)+i_][j_], 0, 0, 0); \
  _Pragma("unroll") for (int i_ = 0; i_ < 4; ++i_) \
  _Pragma("unroll") for (int j_ = 0; j_ < 4; ++j_) \
    acc[(IB)+i_][j_] = __builtin_amdgcn_mfma_f32_16x16x32_bf16(aFh[i_], bFl[j_], acc[(IB)+i_][j_], 0, 0, 0); \
  _Pragma("unroll") for (int i_ = 0; i_ < 4; ++i_) \
  _Pragma("unroll") for (int j_ = 0; j_ < 4; ++j_) \
    acc[(IB)+i_][j_] = __builtin_amdgcn_mfma_f32_16x16x32_bf16(aFl[i_], bFh[j_], acc[(IB)+i_][j_], 0, 0, 0); \
  __builtin_amdgcn_s_setprio(0); } while (0)

#define RD4(DST, BASE, OFS) do { \
  _Pragma("unroll") for (int f_ = 0; f_ < 4; ++f_) \
    DST[f_] = *(const bf16x8*)&(BASE)[(OFS) + f_ * 512 + foff]; } while (0)

#define STAGE2(GSRC, LBASE, KOFF) do { \
  __builtin_amdgcn_global_load_lds(GLB((GSRC) + so0 + (KOFF)), LDSP((LBASE) + (wid << 9)), 16, 0, 0); \
  __builtin_amdgcn_global_load_lds(GLB((GSRC) + so1 + (KOFF)), LDSP((LBASE) + 4096 + (wid << 9)), 16, 0, 0); } while (0)

__global__ __launch_bounds__(512, 2) void gemm_bf16x3_2p(
    const unsigned short* __restrict__ Ahi, const unsigned short* __restrict__ Alo,
    const unsigned short* __restrict__ Bhi, const unsigned short* __restrict__ Blo,
    const float* __restrict__ nmean, const float* __restrict__ nstd,
    const float* __restrict__ eps, float* __restrict__ out,
    int M, int N, int K)
{
  __shared__ __align__(16) unsigned short sA[2][2][256 * 32];
  __shared__ __align__(16) unsigned short sB[2][2][256 * 32];

  const int tid  = threadIdx.x;
  const int wid  = tid >> 6;
  const int lane = tid & 63;
  const int l15  = lane & 15;
  const int kg   = lane >> 4;
  const int wm   = wid >> 2;   // 0..1
  const int wn   = wid & 3;    // 0..3

  const int nbm = M >> 8, nbn = N >> 8, nwg = nbm * nbn;
  const int bid = blockIdx.x;
  const int swz = ((nwg & 7) == 0) ? ((bid & 7) * (nwg >> 3) + (bid >> 3)) : bid;
  const int bm = swz % nbm, bn = swz / nbm;
  const long rowA0 = (long)bm << 8;
  const long rowB0 = (long)bn << 8;

  const unsigned short* gAh = Ahi + rowA0 * K;
  const unsigned short* gAl = Alo + rowA0 * K;
  const unsigned short* gBh = Bhi + rowB0 * K;
  const unsigned short* gBl = Blo + rowB0 * K;

  // staging: thread t feeds 16B chunks e0=tid and e1=tid+512 of each 16KB array
  const int e0 = tid, e1 = tid + 512;
  const int r0 = e0 >> 2, r1 = e1 >> 2;
  const long so0 = (long)r0 * K + (long)(((e0 & 3) ^ ((r0 >> 1) & 3)) << 3);
  const long so1 = (long)r1 * K + (long)(((e1 & 3) ^ ((r1 >> 1) & 3)) << 3);

  // per-lane fragment read offset (elements)
  const int foff = l15 * 32 + ((kg ^ ((l15 >> 1) & 3)) << 3);

  f32x4 acc[8][4];
#pragma unroll
  for (int i = 0; i < 8; ++i)
#pragma unroll
    for (int j = 0; j < 4; ++j) acc[i][j] = (f32x4)0.0f;

  const int nt = K >> 5;

  // prologue: stage tile 0 into buffer 0
  STAGE2(gAh, &sA[0][0][0], 0);
  STAGE2(gAl, &sA[0][1][0], 0);
  STAGE2(gBh, &sB[0][0][0], 0);
  STAGE2(gBl, &sB[0][1][0], 0);
  WAIT_VM0;
  BARRIER0;

  for (int t = 0; t < nt; ++t) {
    const int c = t & 1;
    const long KOFF = (long)(t + 1) << 5;
    const bool pf = (t + 1 < nt);
    unsigned short* nAh = &sA[c ^ 1][0][0];
    unsigned short* nAl = &sA[c ^ 1][1][0];
    unsigned short* nBh = &sB[c ^ 1][0][0];
    unsigned short* nBl = &sB[c ^ 1][1][0];
    bf16x8 aFh[4], aFl[4], bFh[4], bFl[4];

    // P1: all B-frags (tile-resident) + A-frags m-half 0; issue all staging
    RD4(bFh, sB[c][0], wn * 2048);
    RD4(bFl, sB[c][1], wn * 2048);
    RD4(aFh, sA[c][0], wm * 4096);
    RD4(aFl, sA[c][1], wm * 4096);
    if (pf) {
      STAGE2(gAh, nAh, KOFF);
      STAGE2(gAl, nAl, KOFF);
      STAGE2(gBh, nBh, KOFF);
      STAGE2(gBl, nBl, KOFF);
    }
    BARRIER0; WAIT_LGKM0; MFMA_BLOCK3(0); BARRIER0;

    // P2: A-frags m-half 1; tile-end drain + publish
    RD4(aFh, sA[c][0], wm * 4096 + 2048);
    RD4(aFl, sA[c][1], wm * 4096 + 2048);
    BARRIER0; WAIT_LGKM0; MFMA_BLOCK3(4);
    WAIT_VM0;
    BARRIER0;
  }

  // epilogue: C/D layout col=lane&15, row=4*(lane>>4)+r; fused noise
  const float NS = 2.44140625e-4f; // 2^-12
  const long r0o = rowA0 + wm * 128;
  const long c0o = rowB0 + wn * 64;
#pragma unroll
  for (int i = 0; i < 8; ++i)
#pragma unroll
    for (int j = 0; j < 4; ++j) {
      const long col = c0o + j * 16 + l15;
      const float mn = nmean[col];
      const float sd = nstd[col];
#pragma unroll
      for (int r = 0; r < 4; ++r) {
        const long row = r0o + i * 16 + kg * 4 + r;
        const long o = row * N + col;
        out[o] = acc[i][j][r] + (mn + sd * eps[o]) * NS;
      }
    }
}

// Insurance: plain fp32 LDS-tiled GEMM (only for odd shapes / tiny workspace).
__global__ __launch_bounds__(1024) void fb_gemm(
    const float* __restrict__ A, const float* __restrict__ B,
    const float* __restrict__ nmean, const float* __restrict__ nstd,
    const float* __restrict__ eps, float* __restrict__ out,
    int M, int N, int K) {
  __shared__ float sA[32][33];
  __shared__ float sB[32][33];
  const int tx = threadIdx.x & 31, ty = threadIdx.x >> 5;
  const int row = blockIdx.y * 32 + ty;
  const int col = blockIdx.x * 32 + tx;
  float acc = 0.f;
  for (int kt = 0; kt < K; kt += 32) {
    sA[ty][tx] = A[(long)row * K + kt + tx];
    sB[ty][tx] = B[(long)(kt + ty) * N + col];
    __syncthreads();
#pragma unroll
    for (int k = 0; k < 32; ++k) acc += sA[ty][k] * sB[k][tx];
    __syncthreads();
  }
  const long o = (long)row * N + col;
  out[o] = acc + (nmean[col] + nstd[col] * eps[o]) * 2.44140625e-4f;
}

extern "C" void kernel_launch(void* const* d_in, const int* in_sizes, int n_in,
                              void* d_out, int out_size, void* d_ws, size_t ws_size,
                              hipStream_t stream) {
  (void)n_in; (void)out_size;
  const float* x     = (const float*)d_in[0];
  const float* w     = (const float*)d_in[1];
  const float* nmean = (const float*)d_in[2];
  const float* nstd  = (const float*)d_in[3];
  const float* eps   = (const float*)d_in[4];
  float* out = (float*)d_out;

  const int U  = in_sizes[2];
  const int Dk = in_sizes[1] / U;
  const int Bm = in_sizes[0] / Dk;

  const size_t elemsA = (size_t)Bm * Dk;
  const size_t elemsB = (size_t)Dk * U;
  const size_t need = 2 * (elemsA + elemsB) * sizeof(unsigned short);

  const bool ok = (ws_size >= need) &&
                  (Bm % 256 == 0) && (U % 256 == 0) && (Dk % 256 == 0) &&
                  ((elemsA % 8) == 0);

  if (ok) {
    unsigned short* Ahi  = (unsigned short*)d_ws;
    unsigned short* Alo  = Ahi + elemsA;
    unsigned short* BhiT = Alo + elemsA;
    unsigned short* BloT = BhiT + elemsB;
    const long nA = (long)elemsA;
    const int gridA = (int)((nA / 8 + 255) / 256);
    convert_split_k<<<gridA, 256, 0, stream>>>(x, Ahi, Alo, nA);
    transpose_split_k<<<(U >> 4) * (Dk >> 8), 256, 0, stream>>>(w, BhiT, BloT, Dk, U);
    const int nwg = (Bm >> 8) * (U >> 8);
    gemm_bf16x3_2p<<<nwg, 512, 0, stream>>>(Ahi, Alo, BhiT, BloT,
                                            nmean, nstd, eps, out, Bm, U, Dk);
  } else {
    dim3 g(U / 32, Bm / 32);
    fb_gemm<<<g, 1024, 0, stream>>>(x, w, nmean, nstd, eps, out, Bm, U, Dk);
  }
}